// Round 1
// 65.490 us; speedup vs baseline: 1.1316x; 1.1316x over previous
//
#include <hip/hip_runtime.h>

// Two dispatches, no initialization of d_ws needed (re-poison safe):
//   fused_kernel : NBLK blocks write partial (loss, trivial) pairs to ws[2*b], ws[2*b+1]
//   final_kernel : one block recounts pos/neg from target, reduces partials, writes out
//
// ws usage: NBLK*2 floats (NBLK = ceil(n/256) * NJ = 512 at n=8192) -> 4 KB.

#define NJ 16   // j-chunks per i-tile; grid = ceil(n/256) * NJ blocks

__global__ __launch_bounds__(256) void fused_kernel(
        const float* __restrict__ pred,
        const int* __restrict__ target,
        float* __restrict__ ws, int n) {
    __shared__ __align__(16) float s_pj[256];
    int tid = threadIdx.x;
    int b   = blockIdx.x;
    int ib  = b >> 4;        // i-tile   (NJ == 16)
    int jc  = b & (NJ - 1);  // j-chunk
    int i   = ib * 256 + tid;

    // Branch-free pair semantics: invalid/pos-only i -> -1e30 (contributes 0),
    // invalid/non-neg j -> +1e30 (contributes 0). -1e30 - 1e30 = -2e30, no inf.
    float pi = -1e30f;
    float triv = 0.0f;
    if (i < n) {
        float p = pred[i];
        if (target[i] == 1) pi = p;
        if (jc == 0) triv = 1.0f / (p * p + 1e-5f);  // each i counted once
    }

    int jchunk = (n + NJ - 1) / NJ;
    int j0 = jc * jchunk;
    int j1 = min(j0 + jchunk, n);

    float a0 = 0.0f, a1 = 0.0f, a2 = 0.0f, a3 = 0.0f;
    for (int jb = j0; jb < j1; jb += 256) {
        int j = jb + tid;
        float pj = 1e30f;
        if (j < j1 && target[j] == 0) pj = pred[j];
        __syncthreads();            // protect previous iteration's readers
        s_pj[tid] = pj;
        __syncthreads();
        int cnt = min(256, j1 - jb);
        int c4  = cnt >> 2;
        const float4* s4 = (const float4*)s_pj;
        #pragma unroll 8
        for (int k = 0; k < c4; ++k) {
            float4 v = s4[k];       // LDS broadcast read, 16B per ds_read
            a0 += fmaxf(pi - v.x, 0.0f);
            a1 += fmaxf(pi - v.y, 0.0f);
            a2 += fmaxf(pi - v.z, 0.0f);
            a3 += fmaxf(pi - v.w, 0.0f);
        }
        for (int k = c4 << 2; k < cnt; ++k)
            a0 += fmaxf(pi - s_pj[k], 0.0f);
    }
    float acc = (a0 + a1) + (a2 + a3);

    // block reduce (wave64 shuffle + LDS across 4 waves)
    for (int off = 32; off > 0; off >>= 1) {
        acc  += __shfl_down(acc,  off, 64);
        triv += __shfl_down(triv, off, 64);
    }
    __shared__ float s_a[4], s_t[4];
    int lane = tid & 63, wave = tid >> 6;
    if (lane == 0) { s_a[wave] = acc; s_t[wave] = triv; }
    __syncthreads();
    if (tid == 0) {
        ws[2 * b]     = s_a[0] + s_a[1] + s_a[2] + s_a[3];  // partial loss
        ws[2 * b + 1] = s_t[0] + s_t[1] + s_t[2] + s_t[3];  // partial trivial
    }
}

__global__ __launch_bounds__(256) void final_kernel(
        const int* __restrict__ target,
        const float* __restrict__ ws,
        float* __restrict__ out, int n, int nblk) {
    int tid = threadIdx.x;

    // counts (32 KB read, L2-resident; cheaper than an extra dispatch)
    int pos = 0, neg = 0;
    for (int i = tid; i < n; i += 256) {
        int t = target[i];
        pos += (t == 1);
        neg += (t == 0);
    }
    // reduce partials
    float loss = 0.0f, triv = 0.0f;
    for (int b2 = tid; b2 < nblk; b2 += 256) {
        loss += ws[2 * b2];
        triv += ws[2 * b2 + 1];
    }

    for (int off = 32; off > 0; off >>= 1) {
        loss += __shfl_down(loss, off, 64);
        triv += __shfl_down(triv, off, 64);
        pos  += __shfl_down(pos,  off, 64);
        neg  += __shfl_down(neg,  off, 64);
    }
    __shared__ float s_l[4], s_t[4];
    __shared__ int   s_p[4], s_n[4];
    int lane = tid & 63, wave = tid >> 6;
    if (lane == 0) { s_l[wave] = loss; s_t[wave] = triv; s_p[wave] = pos; s_n[wave] = neg; }
    __syncthreads();
    if (tid == 0) {
        float L = s_l[0] + s_l[1] + s_l[2] + s_l[3];
        float T = s_t[0] + s_t[1] + s_t[2] + s_t[3];
        float P = (float)(s_p[0] + s_p[1] + s_p[2] + s_p[3]);
        float G = (float)(s_n[0] + s_n[1] + s_n[2] + s_n[3]);
        out[0] = T / (float)n + L / (P * G);
    }
}

extern "C" void kernel_launch(void* const* d_in, const int* in_sizes, int n_in,
                              void* d_out, int out_size, void* d_ws, size_t ws_size,
                              hipStream_t stream) {
    const float* pred   = (const float*)d_in[0];
    const int*   target = (const int*)d_in[1];
    int n = in_sizes[0];
    float* ws = (float*)d_ws;

    int nti  = (n + 255) / 256;   // i-tiles (32 at n=8192)
    int nblk = nti * NJ;          // 512 blocks

    fused_kernel<<<nblk, 256, 0, stream>>>(pred, target, ws, n);
    final_kernel<<<1, 256, 0, stream>>>(target, ws, (float*)d_out, n, nblk);
}